// Round 5
// baseline (414.149 us; speedup 1.0000x reference)
//
#include <hip/hip_runtime.h>
#include <hip/hip_bf16.h>

// GraphLayer B=8,N=2048,D=512 — Round 5.
//   r4 post-mortem: agg (not scores) dominates (~200us): d-tiling re-read
//   Wbf 4x = 268 MB HBM at the ~2 TB/s a latency-bound K-loop achieves.
//   Change: agg rewritten — block = 32q x FULL d=512, grid (64,8)=512
//   blocks (2/CU). Per 32k chunk: stage W[32x32] (2KB) + Vt[512x32] (32KB)
//   in LDS; W read ONCE (67 MB), Vt L2-resident. den via ones-MFMA (r4,
//   proven). Everything else unchanged from r4.
// Numerics: fp16 Q/K path, W/V bf16 (W reaches ~1e14 — must stay bf16),
// fp32 accum. Expect absmax identical (same values, same chunk order).

#define BATCH 8
#define SEQ   2048
#define DIM   512
#define MSEQ  (BATCH * SEQ)   // 16384

typedef __attribute__((ext_vector_type(8))) short    bf16x8;
typedef __attribute__((ext_vector_type(8))) _Float16 f16x8;
typedef __attribute__((ext_vector_type(4))) float    f32x4;

__device__ __forceinline__ unsigned short f2bf(float f) {
  __hip_bfloat16 h = __float2bfloat16(f);
  union { __hip_bfloat16 h; unsigned short u; } c; c.h = h; return c.u;
}
__device__ __forceinline__ float bf2f(unsigned short u) {
  union { unsigned int u; float f; } c; c.u = ((unsigned int)u) << 16; return c.f;
}
__device__ __forceinline__ unsigned short f2h(float f) {
  union { _Float16 h; unsigned short u; } c; c.h = (_Float16)f; return c.u;
}

__device__ __forceinline__ void async16(const unsigned short* g, unsigned short* l) {
  __builtin_amdgcn_global_load_lds(
      (const __attribute__((address_space(1))) void*)g,
      (__attribute__((address_space(3))) void*)l, 16, 0, 0);
}

// ---------------------------------------------------------------- core ----
// acc[i][j] += A[m][k] * B[n][k]  (NT). DT=0: bf16 MFMA, DT=1: f16 MFMA.
template <int DT>
__device__ __forceinline__ void gemm_mainloop(
    const unsigned short* __restrict__ A, const unsigned short* __restrict__ B,
    int lda, int ldb, int K,
    unsigned short* sA, unsigned short* sB, f32x4 acc[4][4])
{
  const int tid  = threadIdx.x;
  const int lane = tid & 63;
  const int w    = tid >> 6;
  const int wm   = w >> 1, wn = w & 1;
  const int quad = lane >> 4, fcol = lane & 15;
  const int srow = lane >> 2;          // 0..15 within a 16-row chunk
  const int scol = (lane & 3) * 8;     // ushort offset, 16B granules

  for (int k0 = 0; k0 < K; k0 += 32) {
#pragma unroll
    for (int inst = 0; inst < 2; ++inst) {
      const int rbase  = w * 32 + inst * 16;   // wave-uniform
      const int r      = rbase + srow;
      const int ldsoff = rbase * 32;           // row stride 32 ushorts
      async16(A + (size_t)r * lda + k0 + scol, sA + ldsoff);
      async16(B + (size_t)r * ldb + k0 + scol, sB + ldsoff);
    }
    __syncthreads();

#pragma unroll
    for (int i = 0; i < 4; ++i) {
      const int ra = (wm * 64 + i * 16 + fcol) * 32 + quad * 8;
      if constexpr (DT == 0) {
        bf16x8 a = *(const bf16x8*)(sA + ra);
#pragma unroll
        for (int j = 0; j < 4; ++j) {
          const int rbj = (wn * 64 + j * 16 + fcol) * 32 + quad * 8;
          bf16x8 b = *(const bf16x8*)(sB + rbj);
          acc[i][j] = __builtin_amdgcn_mfma_f32_16x16x32_bf16(a, b, acc[i][j], 0, 0, 0);
        }
      } else {
        f16x8 a = *(const f16x8*)(sA + ra);
#pragma unroll
        for (int j = 0; j < 4; ++j) {
          const int rbj = (wn * 64 + j * 16 + fcol) * 32 + quad * 8;
          f16x8 b = *(const f16x8*)(sB + rbj);
          acc[i][j] = __builtin_amdgcn_mfma_f32_16x16x32_f16(a, b, acc[i][j], 0, 0, 0);
        }
      }
    }
    __syncthreads();
  }
}

#define EPI_SETUP                                                  \
  const int lane = threadIdx.x & 63;                               \
  const int w_   = threadIdx.x >> 6;                               \
  const int wm   = w_ >> 1, wn = w_ & 1;                           \
  const int quad = lane >> 4, fcol = lane & 15;

// ----------------------------------------------------------------- cvt ----
__global__ __launch_bounds__(256) void cvt_kernel(
    const float* __restrict__ in, unsigned short* __restrict__ out, int n4)
{
  int i = blockIdx.x * 256 + threadIdx.x;
  if (i >= n4) return;
  float4 v = ((const float4*)in)[i];
  ushort4 h;
  h.x = f2h(v.x); h.y = f2h(v.y); h.z = f2h(v.z); h.w = f2h(v.w);
  ((ushort4*)out)[i] = h;
}

// 3 weight matrices in one launch (blockIdx.y selects)
__global__ __launch_bounds__(256) void cvt_w_kernel(
    const float* __restrict__ w0, const float* __restrict__ w1,
    const float* __restrict__ w2, unsigned short* __restrict__ o0,
    unsigned short* __restrict__ o1, unsigned short* __restrict__ o2, int n4)
{
  int i = blockIdx.x * 256 + threadIdx.x;
  if (i >= n4) return;
  const float* in = (blockIdx.y == 0) ? w0 : (blockIdx.y == 1) ? w1 : w2;
  unsigned short* out = (blockIdx.y == 0) ? o0 : (blockIdx.y == 1) ? o1 : o2;
  float4 v = ((const float4*)in)[i];
  ushort4 h;
  h.x = f2h(v.x); h.y = f2h(v.y); h.z = f2h(v.z); h.w = f2h(v.w);
  ((ushort4*)out)[i] = h;
}

// ------------------------------------------------------------- proj QK ----
// z=0: Q = x@Wq^T+bq ; z=1: K = x@Wk^T+bk   (fp16 in/out, fp32 acc)
__global__ __launch_bounds__(256) void proj_qk_kernel(
    const unsigned short* __restrict__ xh,
    const unsigned short* __restrict__ wq, const unsigned short* __restrict__ wk,
    const float* __restrict__ bq, const float* __restrict__ bk,
    unsigned short* __restrict__ Qh, unsigned short* __restrict__ Kh)
{
  __shared__ unsigned short sA[128 * 32], sB[128 * 32];
  const unsigned short* wh = blockIdx.z ? wk : wq;
  const float* bias        = blockIdx.z ? bk : bq;
  unsigned short* O        = blockIdx.z ? Kh : Qh;
  const int m0 = blockIdx.y * 128, n0 = blockIdx.x * 128;
  f32x4 acc[4][4];
#pragma unroll
  for (int i = 0; i < 4; ++i)
#pragma unroll
    for (int j = 0; j < 4; ++j) acc[i][j] = (f32x4){0.f, 0.f, 0.f, 0.f};

  gemm_mainloop<1>(xh + (size_t)m0 * DIM, wh + (size_t)n0 * DIM,
                   DIM, DIM, DIM, sA, sB, acc);
  EPI_SETUP
#pragma unroll
  for (int i = 0; i < 4; ++i)
#pragma unroll
    for (int j = 0; j < 4; ++j)
#pragma unroll
      for (int r = 0; r < 4; ++r) {
        const int row = m0 + wm * 64 + i * 16 + quad * 4 + r;
        const int col = n0 + wn * 64 + j * 16 + fcol;
        O[(size_t)row * DIM + col] = f2h(acc[i][j][r] + bias[col]);
      }
}

// -------------------------------------------------------------- proj V ----
// Vt[d][m] = Wv[d][:] . x[m][:] + bv[d]   (fp16 in, bf16 out, transposed)
__global__ __launch_bounds__(256) void proj_v_kernel(
    const unsigned short* __restrict__ wvh, const unsigned short* __restrict__ xh,
    const float* __restrict__ bias, unsigned short* __restrict__ Vt)
{
  __shared__ unsigned short sA[128 * 32], sB[128 * 32];
  const int m0 = blockIdx.y * 128, n0 = blockIdx.x * 128;
  f32x4 acc[4][4];
#pragma unroll
  for (int i = 0; i < 4; ++i)
#pragma unroll
    for (int j = 0; j < 4; ++j) acc[i][j] = (f32x4){0.f, 0.f, 0.f, 0.f};

  gemm_mainloop<1>(wvh + (size_t)m0 * DIM, xh + (size_t)n0 * DIM,
                   DIM, DIM, DIM, sA, sB, acc);
  EPI_SETUP
#pragma unroll
  for (int i = 0; i < 4; ++i)
#pragma unroll
    for (int j = 0; j < 4; ++j)
#pragma unroll
      for (int r = 0; r < 4; ++r) {
        const int row = m0 + wm * 64 + i * 16 + quad * 4 + r;   // d
        const int col = n0 + wn * 64 + j * 16 + fcol;           // seq
        Vt[(size_t)row * MSEQ + col] = f2bf(acc[i][j][r] + bias[row]);
      }
}

// -------------------------------------------------------------- scores ----
// Wbf[b][q][k] = bf16( adj[b][q][k] * exp( Q[b][q][:] . K[b][k][:] ) )
// Epilogue: per-wave LDS transpose -> float4 adj loads, ushort4 stores.
#define EPI_STRIDE 68   // floats; 272B rows (16B-aligned), 2-way banks on write
__global__ __launch_bounds__(256) void scores_kernel(
    const unsigned short* __restrict__ Qh, const unsigned short* __restrict__ Kh,
    const float* __restrict__ adj, unsigned short* __restrict__ Wbf)
{
  // arena: K-loop needs 2*8192 B; epilogue needs 4 waves * 16*68*4 B = 17408 B
  __shared__ __align__(16) char smem[4 * 16 * EPI_STRIDE * 4];
  unsigned short* sA = (unsigned short*)smem;
  unsigned short* sB = sA + 128 * 32;
  float* sEpi = (float*)smem;   // safe: K-loop ends with __syncthreads

  const int b  = blockIdx.z;
  const int m0 = blockIdx.y * 128, n0 = blockIdx.x * 128;
  const size_t boff = (size_t)b * SEQ * DIM;
  f32x4 acc[4][4];
#pragma unroll
  for (int i = 0; i < 4; ++i)
#pragma unroll
    for (int j = 0; j < 4; ++j) acc[i][j] = (f32x4){0.f, 0.f, 0.f, 0.f};

  gemm_mainloop<1>(Qh + boff + (size_t)m0 * DIM, Kh + boff + (size_t)n0 * DIM,
                   DIM, DIM, DIM, sA, sB, acc);
  EPI_SETUP
  float* myEpi = sEpi + w_ * (16 * EPI_STRIDE);
  const float* adjb = adj + (size_t)b * SEQ * SEQ;
  unsigned short* wb = Wbf + (size_t)b * SEQ * SEQ;
  const int colg = n0 + wn * 64 + fcol * 4;

#pragma unroll
  for (int i = 0; i < 4; ++i) {
    // transpose: C-fragment -> LDS (wave-private region, no block barrier)
#pragma unroll
    for (int j = 0; j < 4; ++j)
#pragma unroll
      for (int r = 0; r < 4; ++r)
        myEpi[(quad * 4 + r) * EPI_STRIDE + fcol + 16 * j] = acc[i][j][r];
    __builtin_amdgcn_s_waitcnt(0);   // lgkmcnt(0): wave-local ds_write->ds_read
    // coalesced passes: 4 rows per pass, lane owns 4 consecutive cols
#pragma unroll
    for (int p = 0; p < 4; ++p) {
      const int rr = p * 4 + quad;
      const int rowg = m0 + wm * 64 + i * 16 + rr;
      float4 s4 = *(const float4*)(myEpi + rr * EPI_STRIDE + fcol * 4);
      float4 a4 = *(const float4*)(adjb + (size_t)rowg * SEQ + colg);
      ushort4 o;
      o.x = f2bf(a4.x * __expf(s4.x));
      o.y = f2bf(a4.y * __expf(s4.y));
      o.z = f2bf(a4.z * __expf(s4.z));
      o.w = f2bf(a4.w * __expf(s4.w));
      *(ushort4*)(wb + (size_t)rowg * SEQ + colg) = o;
    }
  }
}

// ----------------------------------------------------------------- agg ----
// out[b][q][d] = ( sum_k Wbf[b][q][k] * Vt[d][b*SEQ+k] ) / rowsum_k(Wbf)
// Round 5: block = 32 q-rows x FULL d=512 -> Wbf read exactly once.
// Per 32k chunk: stage W[32x32] (2KB, waves 0-1) + Vt[512x32] (32KB, all).
// Wave w computes 32q x 128d strip: frags [qi 0..1][dj 0..7].
// den via ones-MFMA (proven r4): rowsum lands in C-layout.
__global__ __launch_bounds__(256) void agg_kernel(
    const unsigned short* __restrict__ Wbf, const unsigned short* __restrict__ Vt,
    float* __restrict__ out)
{
  __shared__ unsigned short sA[32 * 32];    // W tile  [32q][32k]
  __shared__ unsigned short sB[512 * 32];   // Vt tile [512d][32k]
  const int b  = blockIdx.y;
  const int q0 = blockIdx.x * 32;
  const int tid = threadIdx.x, lane = tid & 63, w = tid >> 6;
  const int quad = lane >> 4, fcol = lane & 15;
  const int srow = lane >> 2, scol = (lane & 3) * 8;

  const unsigned short* Wb = Wbf + ((size_t)b * SEQ + q0) * SEQ;
  const unsigned short* Vb = Vt + (size_t)b * SEQ;

  f32x4 acc[2][8];        // [qi][dj] — 32q x 128d per wave
  f32x4 acc_den[2];
#pragma unroll
  for (int qi = 0; qi < 2; ++qi) {
    acc_den[qi] = (f32x4){0.f, 0.f, 0.f, 0.f};
#pragma unroll
    for (int dj = 0; dj < 8; ++dj) acc[qi][dj] = (f32x4){0.f, 0.f, 0.f, 0.f};
  }

  bf16x8 ones;
#pragma unroll
  for (int t = 0; t < 8; ++t) ones[t] = (short)0x3F80;   // bf16 1.0

  for (int k0 = 0; k0 < SEQ; k0 += 32) {
    // stage A (W): 32 rows — waves 0,1 each cover 16 rows
    if (w < 2) {
      const int rbase = w * 16;
      async16(Wb + (size_t)(rbase + srow) * SEQ + k0 + scol, sA + rbase * 32);
    }
    // stage B (Vt): 512 rows — 8 insts x 4 waves x 16 rows
#pragma unroll
    for (int inst = 0; inst < 8; ++inst) {
      const int rbase = (inst * 4 + w) * 16;
      async16(Vb + (size_t)(rbase + srow) * MSEQ + k0 + scol, sB + rbase * 32);
    }
    __syncthreads();

    bf16x8 af[2], bfr[8];
#pragma unroll
    for (int qi = 0; qi < 2; ++qi)
      af[qi] = *(const bf16x8*)(sA + (qi * 16 + fcol) * 32 + quad * 8);
#pragma unroll
    for (int dj = 0; dj < 8; ++dj)
      bfr[dj] = *(const bf16x8*)(sB + (w * 128 + dj * 16 + fcol) * 32 + quad * 8);
#pragma unroll
    for (int qi = 0; qi < 2; ++qi) {
      acc_den[qi] = __builtin_amdgcn_mfma_f32_16x16x32_bf16(af[qi], ones, acc_den[qi], 0, 0, 0);
#pragma unroll
      for (int dj = 0; dj < 8; ++dj)
        acc[qi][dj] = __builtin_amdgcn_mfma_f32_16x16x32_bf16(af[qi], bfr[dj], acc[qi][dj], 0, 0, 0);
    }
    __syncthreads();
  }

#pragma unroll
  for (int qi = 0; qi < 2; ++qi)
#pragma unroll
    for (int r = 0; r < 4; ++r) {
      const int row = q0 + qi * 16 + quad * 4 + r;
      const float rd = 1.0f / acc_den[qi][r];
#pragma unroll
      for (int dj = 0; dj < 8; ++dj) {
        const int col = w * 128 + dj * 16 + fcol;
        out[((size_t)b * SEQ + row) * DIM + col] = acc[qi][dj][r] * rd;
      }
    }
}

// -------------------------------------------------------------- launch ----
extern "C" void kernel_launch(void* const* d_in, const int* in_sizes, int n_in,
                              void* d_out, int out_size, void* d_ws, size_t ws_size,
                              hipStream_t stream) {
  const float* x   = (const float*)d_in[0];
  const float* adj = (const float*)d_in[1];
  const float* Wq  = (const float*)d_in[2];
  const float* bq  = (const float*)d_in[3];
  const float* Wk  = (const float*)d_in[4];
  const float* bk  = (const float*)d_in[5];
  const float* Wv  = (const float*)d_in[6];
  const float* bv  = (const float*)d_in[7];
  float* out = (float*)d_out;

  const size_t NX = (size_t)MSEQ * DIM;   // 8,388,608
  const size_t NW = (size_t)DIM * DIM;    // 262,144
  unsigned short* ws = (unsigned short*)d_ws;
  unsigned short* xh  = ws;               // fp16
  unsigned short* wqh = xh + NX;
  unsigned short* wkh = wqh + NW;
  unsigned short* wvh = wkh + NW;
  unsigned short* Qh  = wvh + NW;         // fp16
  unsigned short* Kh  = Qh + NX;          // fp16
  unsigned short* Vt  = Kh + NX;          // bf16, transposed [DIM][MSEQ]
  unsigned short* Wbf = Vt + NX;          // bf16, MSEQ*SEQ

  // 1. fp32 -> fp16 conversions (2 launches)
  cvt_kernel<<<(int)(NX / 4 / 256), 256, 0, stream>>>(x, xh, (int)(NX / 4));
  dim3 cw((int)(NW / 4 / 256), 3);
  cvt_w_kernel<<<cw, 256, 0, stream>>>(Wq, Wk, Wv, wqh, wkh, wvh, (int)(NW / 4));

  // 2. projections (2 launches)
  dim3 pq(DIM / 128, MSEQ / 128, 2);       // (4, 128, 2) — z: Q or K
  proj_qk_kernel<<<pq, 256, 0, stream>>>(xh, wqh, wkh, bq, bk, Qh, Kh);
  dim3 pv(MSEQ / 128, DIM / 128);          // (128, 4)
  proj_v_kernel<<<pv, 256, 0, stream>>>(wvh, xh, bv, Vt);

  // 3. scores + 4. aggregate
  dim3 sg(SEQ / 128, SEQ / 128, BATCH);    // (16, 16, 8)
  scores_kernel<<<sg, 256, 0, stream>>>(Qh, Kh, adj, Wbf);
  dim3 ag(SEQ / 32, BATCH);                // (64, 8) = 512 blocks
  agg_kernel<<<ag, 256, 0, stream>>>(Wbf, Vt, out);
}